// Round 1
// baseline (166.928 us; speedup 1.0000x reference)
//
#include <hip/hip_runtime.h>

#define NS 64     // samples per batch
#define D  256    // hidden dims
#define O  10     // output dim

// ---------------- W2 transpose (for coalesced backward reads) ----------------
__global__ __launch_bounds__(1024) void transpose_kernel(
    const float* __restrict__ W2, float* __restrict__ W2T)
{
    __shared__ float tile[32][33];
    int bx = blockIdx.x & 7, by = blockIdx.x >> 3;
    int tx = threadIdx.x & 31, ty = threadIdx.x >> 5;
    tile[ty][tx] = W2[(by * 32 + ty) * D + bx * 32 + tx];
    __syncthreads();
    W2T[(bx * 32 + ty) * D + by * 32 + tx] = tile[tx][ty];
}

// ---------------- forward: h1, S1, h2, G2 per sample ----------------
__global__ __launch_bounds__(256) void fwd_kernel(
    const float* __restrict__ x1, const float* __restrict__ x2,
    const float* __restrict__ W1, const float* __restrict__ b1,
    const float* __restrict__ W2, const float* __restrict__ b2,
    const float* __restrict__ W3,
    float* __restrict__ h1o, float* __restrict__ S1o,
    float* __restrict__ h2o, float* __restrict__ G2o)
{
    int s = blockIdx.x;           // 0..127 (0..63 -> x1, 64..127 -> x2)
    int t = threadIdx.x;          // column index 0..255
    const float* x = (s < NS) ? (x1 + s * D) : (x2 + (s - NS) * D);
    __shared__ float xs[D];
    __shared__ float hs[D];
    xs[t] = x[t];
    __syncthreads();

    float acc = b1[t];
    #pragma unroll 8
    for (int k = 0; k < D; ++k) acc = fmaf(xs[k], W1[k * D + t], acc);
    float h1v = tanhf(acc);
    h1o[s * D + t] = h1v;
    S1o[s * D + t] = 1.0f - h1v * h1v;
    hs[t] = h1v;
    __syncthreads();

    acc = b2[t];
    #pragma unroll 8
    for (int k = 0; k < D; ++k) acc = fmaf(hs[k], W2[k * D + t], acc);
    float h2v = tanhf(acc);
    h2o[s * D + t] = h2v;
    float s2 = 1.0f - h2v * h2v;
    #pragma unroll
    for (int a = 0; a < O; ++a)
        G2o[(s * D + t) * O + a] = s2 * W3[t * O + a];
}

// ---------------- backward: G1[s,i,a] = S1[s,i] * sum_j W2[i,j]*G2[s,j,a] ----
__global__ __launch_bounds__(256) void bwd_kernel(
    const float* __restrict__ W2T, const float* __restrict__ S1,
    const float* __restrict__ G2, float* __restrict__ G1)
{
    int s = blockIdx.x, t = threadIdx.x;   // t = row i
    __shared__ float g2s[D * O];           // 10 KB
    for (int idx = t; idx < D * O; idx += 256) g2s[idx] = G2[s * D * O + idx];
    __syncthreads();

    float acc[O];
    #pragma unroll
    for (int a = 0; a < O; ++a) acc[a] = 0.0f;
    for (int j = 0; j < D; ++j) {
        float w = W2T[j * D + t];          // coalesced across t
        #pragma unroll
        for (int a = 0; a < O; ++a) acc[a] = fmaf(w, g2s[j * O + a], acc[a]);
    }
    float s1 = S1[s * D + t];
    #pragma unroll
    for (int a = 0; a < O; ++a) G1[(s * D + t) * O + a] = s1 * acc[a];
}

// ---------------- three 64x64 dot matrices: x1.x2, h1.h1', h2.h2' ----------
__global__ __launch_bounds__(256) void dots_kernel(
    const float* __restrict__ x1, const float* __restrict__ x2,
    const float* __restrict__ h1, const float* __restrict__ h2,
    float* __restrict__ dots)   // [3][64][64]
{
    int n = blockIdx.x, which = blockIdx.y;
    const float* A; const float* B;
    if (which == 0)      { A = x1 + n * D; B = x2; }
    else if (which == 1) { A = h1 + n * D; B = h1 + NS * D; }
    else                 { A = h2 + n * D; B = h2 + NS * D; }
    __shared__ float as[D];
    int t = threadIdx.x;
    as[t] = A[t];
    __syncthreads();
    int wave = t >> 6, lane = t & 63;
    for (int m = wave; m < NS; m += 4) {
        const float* Bv = B + m * D;
        float v = as[lane] * Bv[lane]
                + as[64 + lane] * Bv[64 + lane]
                + as[128 + lane] * Bv[128 + lane]
                + as[192 + lane] * Bv[192 + lane];
        #pragma unroll
        for (int off = 32; off > 0; off >>= 1) v += __shfl_xor(v, off);
        if (lane == 0) dots[(which * NS + n) * NS + m] = v;
    }
}

// ---------------- per-pair 10x10 kernel tile ----------------
__global__ __launch_bounds__(256) void pair_kernel(
    const float* __restrict__ G1, const float* __restrict__ G2,
    const float* __restrict__ dots, float* __restrict__ out)
{
    int n = blockIdx.x >> 6;   // blockIdx.x = n*64 + m
    int m = blockIdx.x & 63;
    __shared__ float g1n[D * O], g1m[D * O], g2n[D * O], g2m[D * O];  // 40 KB
    int t = threadIdx.x;
    const float* p1n = G1 + n * D * O;
    const float* p1m = G1 + (NS + m) * D * O;
    const float* p2n = G2 + n * D * O;
    const float* p2m = G2 + (NS + m) * D * O;
    for (int idx = t; idx < D * O; idx += 256) {
        g1n[idx] = p1n[idx]; g1m[idx] = p1m[idx];
        g2n[idx] = p2n[idx]; g2m[idx] = p2m[idx];
    }
    __syncthreads();
    if (t < O * O) {
        int a = t / O, b = t % O;
        float acc1 = 0.0f, acc2 = 0.0f;
        for (int i = 0; i < D; ++i) {
            acc1 = fmaf(g1n[i * O + a], g1m[i * O + b], acc1);
            acc2 = fmaf(g2n[i * O + a], g2m[i * O + b], acc2);
        }
        float cx  = 1.0f + dots[0 * NS * NS + n * NS + m];
        float ch1 = 1.0f + dots[1 * NS * NS + n * NS + m];
        float ch2 = 1.0f + dots[2 * NS * NS + n * NS + m];
        float val = cx * acc1 + ch1 * acc2 + ((a == b) ? ch2 : 0.0f);
        out[blockIdx.x * (O * O) + t] = val;
    }
}

extern "C" void kernel_launch(void* const* d_in, const int* in_sizes, int n_in,
                              void* d_out, int out_size, void* d_ws, size_t ws_size,
                              hipStream_t stream) {
    const float* x1 = (const float*)d_in[0];
    const float* x2 = (const float*)d_in[1];
    const float* W1 = (const float*)d_in[2];
    const float* b1 = (const float*)d_in[3];
    const float* W2 = (const float*)d_in[4];
    const float* b2 = (const float*)d_in[5];
    const float* W3 = (const float*)d_in[6];
    // b3 (d_in[7]) does not enter the Jacobian.

    float* ws   = (float*)d_ws;
    float* h1   = ws;                     // 128*256
    float* S1   = h1 + 128 * D;           // 128*256
    float* h2   = S1 + 128 * D;           // 128*256
    float* G2   = h2 + 128 * D;           // 128*256*10
    float* G1   = G2 + 128 * D * O;       // 128*256*10
    float* W2T  = G1 + 128 * D * O;       // 256*256
    float* dots = W2T + D * D;            // 3*64*64
    float* out  = (float*)d_out;

    hipLaunchKernelGGL(transpose_kernel, dim3(64), dim3(1024), 0, stream, W2, W2T);
    hipLaunchKernelGGL(fwd_kernel, dim3(128), dim3(256), 0, stream,
                       x1, x2, W1, b1, W2, b2, W3, h1, S1, h2, G2);
    hipLaunchKernelGGL(bwd_kernel, dim3(128), dim3(256), 0, stream, W2T, S1, G2, G1);
    hipLaunchKernelGGL(dots_kernel, dim3(64, 3), dim3(256), 0, stream, x1, x2, h1, h2, dots);
    hipLaunchKernelGGL(pair_kernel, dim3(4096), dim3(256), 0, stream, G1, G2, dots, out);
}

// Round 2
// 144.394 us; speedup vs baseline: 1.1561x; 1.1561x over previous
//
#include <hip/hip_runtime.h>

#define NS 64     // samples per batch
#define D  256    // hidden dims
#define O  10     // output dim
#define TK 32     // GEMM K-chunk
#define LSTR 36   // LDS row stride (TK + 4 pad, keeps 16B align, kills conflicts)

// ---------------- prep1: forward passes (blocks 0..127) + W2 transpose (128..191) ----
__global__ __launch_bounds__(256) void prep1_kernel(
    const float* __restrict__ x1, const float* __restrict__ x2,
    const float* __restrict__ W1, const float* __restrict__ b1,
    const float* __restrict__ W2, const float* __restrict__ b2,
    const float* __restrict__ W3,
    float* __restrict__ h1o, float* __restrict__ S1o,
    float* __restrict__ h2o, float* __restrict__ G2L,
    float* __restrict__ W2T)
{
    int t = threadIdx.x;
    if (blockIdx.x >= 128) {
        // W2 transpose: 64 blocks, 32x32 tiles, 256 threads (8 rows/pass x 4)
        int blk = blockIdx.x - 128;
        int bx = blk & 7, by = blk >> 3;
        __shared__ float tile[32][33];
        int tx = t & 31, ty = t >> 5;          // ty 0..7
        #pragma unroll
        for (int r = 0; r < 4; ++r)
            tile[ty + 8 * r][tx] = W2[(by * 32 + ty + 8 * r) * D + bx * 32 + tx];
        __syncthreads();
        #pragma unroll
        for (int r = 0; r < 4; ++r)
            W2T[(bx * 32 + ty + 8 * r) * D + by * 32 + tx] = tile[tx][ty + 8 * r];
        return;
    }

    int s = blockIdx.x;                        // 0..127
    const float* x = (s < NS) ? (x1 + s * D) : (x2 + (s - NS) * D);
    __shared__ float xs[D];
    __shared__ float hs[D];
    xs[t] = x[t];
    __syncthreads();

    float acc = b1[t];
    #pragma unroll 8
    for (int k = 0; k < D; ++k) acc = fmaf(xs[k], W1[k * D + t], acc);
    float h1v = tanhf(acc);
    h1o[s * D + t] = h1v;
    S1o[s * D + t] = 1.0f - h1v * h1v;
    hs[t] = h1v;
    __syncthreads();

    acc = b2[t];
    #pragma unroll 8
    for (int k = 0; k < D; ++k) acc = fmaf(hs[k], W2[k * D + t], acc);
    float h2v = tanhf(acc);
    h2o[s * D + t] = h2v;
    float s2 = 1.0f - h2v * h2v;
    // G2 in [s][a][i] layout (K-contiguous rows for the GEMM)
    #pragma unroll
    for (int a = 0; a < O; ++a)
        G2L[(s * O + a) * D + t] = s2 * W3[t * O + a];
}

// ---------------- prep2: backward G1 (blocks 0..127) + dot matrices (128..319) ----
__global__ __launch_bounds__(256) void prep2_kernel(
    const float* __restrict__ W2T, const float* __restrict__ S1,
    const float* __restrict__ G2L, float* __restrict__ G1L,
    const float* __restrict__ x1, const float* __restrict__ x2,
    const float* __restrict__ h1, const float* __restrict__ h2,
    float* __restrict__ dots)
{
    int t = threadIdx.x;
    if (blockIdx.x < 128) {
        int s = blockIdx.x;
        __shared__ float g2s[O * D];           // [a][j], 10 KB
        for (int idx = t; idx < D * O; idx += 256) g2s[idx] = G2L[s * D * O + idx];
        __syncthreads();

        float acc[O];
        #pragma unroll
        for (int a = 0; a < O; ++a) acc[a] = 0.0f;
        #pragma unroll 4
        for (int j = 0; j < D; ++j) {
            float w = W2T[j * D + t];          // coalesced across t
            #pragma unroll
            for (int a = 0; a < O; ++a) acc[a] = fmaf(w, g2s[a * D + j], acc[a]);
        }
        float s1 = S1[s * D + t];
        #pragma unroll
        for (int a = 0; a < O; ++a) G1L[(s * O + a) * D + t] = s1 * acc[a];
        return;
    }

    // dots: 192 blocks: which = idx>>6, n = idx&63
    int idx = blockIdx.x - 128;
    int which = idx >> 6, n = idx & 63;
    const float* A; const float* B;
    if (which == 0)      { A = x1 + n * D; B = x2; }
    else if (which == 1) { A = h1 + n * D; B = h1 + NS * D; }
    else                 { A = h2 + n * D; B = h2 + NS * D; }
    __shared__ float as[D];
    as[t] = A[t];
    __syncthreads();
    int wave = t >> 6, lane = t & 63;
    for (int m = wave; m < NS; m += 4) {
        const float* Bv = B + m * D;
        float v = as[lane] * Bv[lane]
                + as[64 + lane] * Bv[64 + lane]
                + as[128 + lane] * Bv[128 + lane]
                + as[192 + lane] * Bv[192 + lane];
        #pragma unroll
        for (int off = 32; off > 0; off >>= 1) v += __shfl_xor(v, off);
        if (lane == 0) dots[(which * NS + n) * NS + m] = v;
    }
}

// ---------------- dual 640x640x256 GEMM + NTK combine epilogue ----------------
// P1 = M1 @ M1'^T, P2 = M2 @ M2'^T where M rows are [n*O+a][i]; out combines with dots.
__global__ __launch_bounds__(256) void ntk_gemm_kernel(
    const float* __restrict__ G1L, const float* __restrict__ G2L,
    const float* __restrict__ dots, float* __restrict__ out)
{
    int by = blockIdx.x / 10, bx = blockIdx.x % 10;   // 64x64 output tile
    __shared__ float A1[64 * LSTR], B1[64 * LSTR], A2[64 * LSTR], B2[64 * LSTR]; // 36 KB
    int t = threadIdx.x;
    int tx = t & 15, ty = t >> 4;

    float acc1[4][4], acc2[4][4];
    #pragma unroll
    for (int i = 0; i < 4; ++i)
        #pragma unroll
        for (int j = 0; j < 4; ++j) { acc1[i][j] = 0.0f; acc2[i][j] = 0.0f; }

    const float* arow1 = G1L + (by * 64) * D;         // batch-1 rows
    const float* brow1 = G1L + (640 + bx * 64) * D;   // batch-2 rows
    const float* arow2 = G2L + (by * 64) * D;
    const float* brow2 = G2L + (640 + bx * 64) * D;

    for (int kc = 0; kc < D; kc += TK) {
        __syncthreads();
        // stage 4 tiles of 64x32 floats; 512 float4 each; 2 float4/thread/tile
        #pragma unroll
        for (int u = 0; u < 2; ++u) {
            int idx = t + u * 256;
            int r = idx >> 3, c4 = idx & 7;
            int goff = r * D + kc + c4 * 4;
            int loff = r * LSTR + c4 * 4;
            *(float4*)&A1[loff] = *(const float4*)&arow1[goff];
            *(float4*)&B1[loff] = *(const float4*)&brow1[goff];
            *(float4*)&A2[loff] = *(const float4*)&arow2[goff];
            *(float4*)&B2[loff] = *(const float4*)&brow2[goff];
        }
        __syncthreads();
        #pragma unroll
        for (int kk = 0; kk < TK; kk += 4) {
            float4 a1[4], b1v[4], a2[4], b2v[4];
            #pragma unroll
            for (int i = 0; i < 4; ++i) {
                a1[i] = *(const float4*)&A1[(4 * ty + i) * LSTR + kk];
                a2[i] = *(const float4*)&A2[(4 * ty + i) * LSTR + kk];
            }
            #pragma unroll
            for (int j = 0; j < 4; ++j) {
                b1v[j] = *(const float4*)&B1[(tx + 16 * j) * LSTR + kk];
                b2v[j] = *(const float4*)&B2[(tx + 16 * j) * LSTR + kk];
            }
            #pragma unroll
            for (int i = 0; i < 4; ++i)
                #pragma unroll
                for (int j = 0; j < 4; ++j) {
                    acc1[i][j] = fmaf(a1[i].x, b1v[j].x, acc1[i][j]);
                    acc1[i][j] = fmaf(a1[i].y, b1v[j].y, acc1[i][j]);
                    acc1[i][j] = fmaf(a1[i].z, b1v[j].z, acc1[i][j]);
                    acc1[i][j] = fmaf(a1[i].w, b1v[j].w, acc1[i][j]);
                    acc2[i][j] = fmaf(a2[i].x, b2v[j].x, acc2[i][j]);
                    acc2[i][j] = fmaf(a2[i].y, b2v[j].y, acc2[i][j]);
                    acc2[i][j] = fmaf(a2[i].z, b2v[j].z, acc2[i][j]);
                    acc2[i][j] = fmaf(a2[i].w, b2v[j].w, acc2[i][j]);
                }
        }
    }

    // epilogue: R=n*10+a, C=m*10+b; out[n,m,a,b] = cx*P1 + ch1*P2 + (a==b)*ch2
    #pragma unroll
    for (int i = 0; i < 4; ++i) {
        int R = by * 64 + 4 * ty + i;
        int n = R / 10, a = R - n * 10;
        #pragma unroll
        for (int j = 0; j < 4; ++j) {
            int C = bx * 64 + tx + 16 * j;
            int m = C / 10, b = C - m * 10;
            float cx  = 1.0f + dots[0 * NS * NS + n * NS + m];
            float ch1 = 1.0f + dots[1 * NS * NS + n * NS + m];
            float val = cx * acc1[i][j] + ch1 * acc2[i][j];
            if (a == b) val += 1.0f + dots[2 * NS * NS + n * NS + m];
            out[(n * NS + m) * (O * O) + a * O + b] = val;
        }
    }
}

extern "C" void kernel_launch(void* const* d_in, const int* in_sizes, int n_in,
                              void* d_out, int out_size, void* d_ws, size_t ws_size,
                              hipStream_t stream) {
    const float* x1 = (const float*)d_in[0];
    const float* x2 = (const float*)d_in[1];
    const float* W1 = (const float*)d_in[2];
    const float* b1 = (const float*)d_in[3];
    const float* W2 = (const float*)d_in[4];
    const float* b2 = (const float*)d_in[5];
    const float* W3 = (const float*)d_in[6];
    // b3 (d_in[7]) does not enter the Jacobian.

    float* ws   = (float*)d_ws;
    float* h1   = ws;                     // 128*256
    float* S1   = h1 + 128 * D;           // 128*256
    float* h2   = S1 + 128 * D;           // 128*256
    float* G2L  = h2 + 128 * D;           // 1280*256  ([s*O+a][i])
    float* G1L  = G2L + 1280 * D;         // 1280*256
    float* W2T  = G1L + 1280 * D;         // 256*256
    float* dots = W2T + D * D;            // 3*64*64
    float* out  = (float*)d_out;

    hipLaunchKernelGGL(prep1_kernel, dim3(192), dim3(256), 0, stream,
                       x1, x2, W1, b1, W2, b2, W3, h1, S1, h2, G2L, W2T);
    hipLaunchKernelGGL(prep2_kernel, dim3(320), dim3(256), 0, stream,
                       W2T, S1, G2L, G1L, x1, x2, h1, h2, dots);
    hipLaunchKernelGGL(ntk_gemm_kernel, dim3(100), dim3(256), 0, stream,
                       G1L, G2L, dots, out);
}